// Round 1
// baseline (451.837 us; speedup 1.0000x reference)
//
#include <hip/hip_runtime.h>
#include <math.h>

#define BB 32
#define TT 4096
#define HH 512
#define MM 2048
#define VV 128
#define KK 8

// 1/sqrt(512)
#define INV_SQRT_H 0.044194173824159216f

// ---------------------------------------------------------------------------
// q[b,j] = sum_h query[b,h] * q_w[h,j] + q_b[j]
__global__ __launch_bounds__(512) void qproj_kernel(
    const float* __restrict__ query, const float* __restrict__ q_w,
    const float* __restrict__ q_b, float* __restrict__ q) {
  int b = blockIdx.x, j = threadIdx.x;
  __shared__ __align__(16) float qs[HH];
  qs[j] = query[b * HH + j];
  __syncthreads();
  float acc = q_b[j];
#pragma unroll 8
  for (int h = 0; h < HH; ++h) acc = fmaf(qs[h], q_w[h * HH + j], acc);
  q[b * HH + j] = acc;
}

// ---------------------------------------------------------------------------
// qk[b,h] = sum_j q[b,j] * k_w[h,j]   (q @ k_w^T)
// qb_dot[b] = sum_j q[b,j] * k_b[j]
__global__ __launch_bounds__(512) void kproj_kernel(
    const float* __restrict__ q, const float* __restrict__ k_w,
    const float* __restrict__ k_b, float* __restrict__ qk,
    float* __restrict__ qb_dot) {
  int b = blockIdx.x, tid = threadIdx.x;
  int lane = tid & 63, wave = tid >> 6;
  __shared__ __align__(16) float qs[HH];
  qs[tid] = q[b * HH + tid];
  __syncthreads();
  const float4* qr = (const float4*)qs;
  for (int h = wave; h < HH; h += 8) {
    const float4* kr = (const float4*)(k_w + (size_t)h * HH);
    float4 a0 = kr[lane], a1 = kr[lane + 64];
    float4 b0 = qr[lane], b1 = qr[lane + 64];
    float acc = a0.x * b0.x + a0.y * b0.y + a0.z * b0.z + a0.w * b0.w +
                a1.x * b1.x + a1.y * b1.y + a1.z * b1.z + a1.w * b1.w;
#pragma unroll
    for (int off = 32; off; off >>= 1) acc += __shfl_down(acc, off);
    if (lane == 0) qk[b * HH + h] = acc;
  }
  if (wave == 0) {
    float acc = 0.f;
    for (int j = lane; j < HH; j += 64) acc = fmaf(qs[j], k_b[j], acc);
#pragma unroll
    for (int off = 32; off; off >>= 1) acc += __shfl_down(acc, off);
    if (lane == 0) qb_dot[b] = acc;
  }
}

// ---------------------------------------------------------------------------
// scores[b,m] = (qk[b] . enc[b, last_pos(m), :] + qb_dot[b]) / sqrt(H)
// One wave per (b,m). 134 MB of enc rows -> HBM-bound.
__global__ __launch_bounds__(256) void score_kernel(
    const float* __restrict__ enc, const float* __restrict__ qk,
    const float* __restrict__ qb_dot, const int* __restrict__ num_pairs,
    float* __restrict__ scores) {
  int gw = (blockIdx.x * 256 + threadIdx.x) >> 6;
  int lane = threadIdx.x & 63;
  int b = gw >> 11;          // / MM
  int m = gw & (MM - 1);
  int L = min(2 * num_pairs[0], TT - 3);
  float qbd = qb_dot[b];
  float s;
  if (m < L) {               // uniform across the wave (m is per-wave)
    int p = m + MM * ((L - 1 - m) / MM);   // last_pos; in [0, L-1] <= T-4
    const float4* row = (const float4*)(enc + ((size_t)b * TT + p) * HH);
    const float4* qr = (const float4*)(qk + (size_t)b * HH);
    float4 a0 = row[lane], a1 = row[lane + 64];
    float4 b0 = qr[lane], b1 = qr[lane + 64];
    float acc = a0.x * b0.x + a0.y * b0.y + a0.z * b0.z + a0.w * b0.w +
                a1.x * b1.x + a1.y * b1.y + a1.z * b1.z + a1.w * b1.w;
#pragma unroll
    for (int off = 32; off; off >>= 1) acc += __shfl_down(acc, off);
    s = (acc + qbd) * INV_SQRT_H;
  } else {
    // invalid slot: memory row is zeroed -> k = k_b -> raw = q.k_b
    s = qbd * INV_SQRT_H;
  }
  if (lane == 0) scores[b * MM + m] = s;
}

// ---------------------------------------------------------------------------
// Per batch: top-8 (lowest-index tie-break, matching lax.top_k), softmax,
// retrieved + query, @ out_w + out_b.
__global__ __launch_bounds__(256) void finalize_kernel(
    const float* __restrict__ enc, const float* __restrict__ scores,
    const float* __restrict__ query, const float* __restrict__ out_w,
    const float* __restrict__ out_b, const int* __restrict__ num_pairs,
    float* __restrict__ out) {
  int b = blockIdx.x, tid = threadIdx.x;
  __shared__ float sv[MM];
  __shared__ float rv[256];
  __shared__ int ri[256];
  __shared__ float topv[KK];
  __shared__ int topi[KK];
  __shared__ float rq[HH];

  for (int i = tid; i < MM; i += 256) sv[i] = scores[b * MM + i];
  __syncthreads();

  for (int k = 0; k < KK; ++k) {
    float best = -INFINITY;
    int bi = 0x7FFFFFFF;
    for (int i = tid; i < MM; i += 256) {
      float v = sv[i];
      if (v > best) { best = v; bi = i; }   // first hit = lowest idx in subset
    }
    rv[tid] = best;
    ri[tid] = bi;
    __syncthreads();
    for (int s = 128; s; s >>= 1) {
      if (tid < s) {
        float ov = rv[tid + s];
        int oi = ri[tid + s];
        if (ov > rv[tid] || (ov == rv[tid] && oi < ri[tid])) {
          rv[tid] = ov;
          ri[tid] = oi;
        }
      }
      __syncthreads();
    }
    if (tid == 0) {
      topv[k] = rv[0];
      topi[k] = ri[0];
      sv[ri[0]] = -INFINITY;
    }
    __syncthreads();
  }

  // softmax over the 8 kept values (redundant per thread; trivial)
  float mx = topv[0];
#pragma unroll
  for (int k = 1; k < KK; ++k) mx = fmaxf(mx, topv[k]);
  float p[KK];
  float se = 0.f;
#pragma unroll
  for (int k = 0; k < KK; ++k) { p[k] = expf(topv[k] - mx); se += p[k]; }
  float inv = 1.f / se;

  int L = min(2 * num_pairs[0], TT - 3);
  // retrieved + query_hidden into LDS
  for (int h = tid; h < HH; h += 256) {
    float acc = query[b * HH + h];
#pragma unroll
    for (int k = 0; k < KK; ++k) {
      int m = topi[k];
      if (m < L) {
        int pp = m + MM * ((L - 1 - m) / MM);
        acc = fmaf(p[k] * inv, enc[((size_t)b * TT + pp) * HH + h], acc);
      }
    }
    rq[h] = acc;
  }
  __syncthreads();

  // logits = rq @ out_w + out_b   (coalesced over v)
  if (tid < VV) {
    float acc = out_b[tid];
#pragma unroll 8
    for (int h = 0; h < HH; ++h) acc = fmaf(rq[h], out_w[h * VV + tid], acc);
    out[b * VV + tid] = acc;
  }
}

// ---------------------------------------------------------------------------
extern "C" void kernel_launch(void* const* d_in, const int* in_sizes, int n_in,
                              void* d_out, int out_size, void* d_ws,
                              size_t ws_size, hipStream_t stream) {
  const float* enc = (const float*)d_in[0];
  const float* query = (const float*)d_in[1];
  const int* num_pairs = (const int*)d_in[2];
  const float* q_w = (const float*)d_in[3];
  const float* q_b = (const float*)d_in[4];
  const float* k_w = (const float*)d_in[5];
  const float* k_b = (const float*)d_in[6];
  const float* out_w = (const float*)d_in[7];
  const float* out_b = (const float*)d_in[8];
  float* out = (float*)d_out;

  char* ws = (char*)d_ws;
  float* q = (float*)(ws);                 // 32*512*4   = 64 KB
  float* qk = (float*)(ws + 65536);        // 32*512*4   = 64 KB
  float* qbd = (float*)(ws + 131072);      // 32*4       (padded to 1 KB)
  float* scores = (float*)(ws + 132096);   // 32*2048*4  = 256 KB

  hipLaunchKernelGGL(qproj_kernel, dim3(BB), dim3(HH), 0, stream,
                     query, q_w, q_b, q);
  hipLaunchKernelGGL(kproj_kernel, dim3(BB), dim3(HH), 0, stream,
                     q, k_w, k_b, qk, qbd);
  hipLaunchKernelGGL(score_kernel, dim3(BB * MM / 4), dim3(256), 0, stream,
                     enc, qk, qbd, num_pairs, scores);
  hipLaunchKernelGGL(finalize_kernel, dim3(BB), dim3(256), 0, stream,
                     enc, scores, query, out_w, out_b, num_pairs, out);
}

// Round 2
// 449.747 us; speedup vs baseline: 1.0046x; 1.0046x over previous
//
#include <hip/hip_runtime.h>
#include <math.h>

#define BB 32
#define TT 4096
#define HH 512
#define MM 2048
#define VV 128
#define KK 8

// 1/sqrt(512)
#define INV_SQRT_H 0.044194173824159216f

// ---------------------------------------------------------------------------
// Fused: q[b] = query[b]@q_w + q_b, then qk[b,h] = q[b].k_w[h,:],
// qb_dot[b] = q[b].k_b.  One block per batch, 512 threads (8 waves).
__global__ __launch_bounds__(512) void qk_kernel(
    const float* __restrict__ query, const float* __restrict__ q_w,
    const float* __restrict__ q_b, const float* __restrict__ k_w,
    const float* __restrict__ k_b, float* __restrict__ qk,
    float* __restrict__ qb_dot) {
  int b = blockIdx.x, tid = threadIdx.x;
  int lane = tid & 63, wave = tid >> 6;
  __shared__ __align__(16) float qs[HH];
  __shared__ __align__(16) float qv[HH];
  qs[tid] = query[b * HH + tid];
  __syncthreads();
  float acc = q_b[tid];
#pragma unroll 8
  for (int h = 0; h < HH; ++h) acc = fmaf(qs[h], q_w[h * HH + tid], acc);
  qv[tid] = acc;
  __syncthreads();

  const float4* qr = (const float4*)qv;
  float4 b0 = qr[lane], b1 = qr[lane + 64];   // q row, read from LDS once
  for (int h = wave; h < HH; h += 8) {
    const float4* kr = (const float4*)(k_w + (size_t)h * HH);
    float4 a0 = kr[lane], a1 = kr[lane + 64];
    float d = a0.x * b0.x + a0.y * b0.y + a0.z * b0.z + a0.w * b0.w +
              a1.x * b1.x + a1.y * b1.y + a1.z * b1.z + a1.w * b1.w;
#pragma unroll
    for (int off = 32; off; off >>= 1) d += __shfl_down(d, off);
    if (lane == 0) qk[b * HH + h] = d;
  }
  if (wave == 0) {
    float d = 0.f;
    for (int j = lane; j < HH; j += 64) d = fmaf(qv[j], k_b[j], d);
#pragma unroll
    for (int off = 32; off; off >>= 1) d += __shfl_down(d, off);
    if (lane == 0) qb_dot[b] = d;
  }
}

// ---------------------------------------------------------------------------
// scores[b,m] = (qk[b] . enc[b, last_pos(m), :] + qb_dot[b]) / sqrt(H)
// One wave per (b,m). ~128 MB of enc rows -> HBM-bound floor (~21 us).
__global__ __launch_bounds__(256) void score_kernel(
    const float* __restrict__ enc, const float* __restrict__ qk,
    const float* __restrict__ qb_dot, const int* __restrict__ num_pairs,
    float* __restrict__ scores) {
  int gw = (blockIdx.x * 256 + threadIdx.x) >> 6;
  int lane = threadIdx.x & 63;
  int b = gw >> 11;          // / MM
  int m = gw & (MM - 1);
  int L = min(2 * num_pairs[0], TT - 3);
  float qbd = qb_dot[b];
  float s;
  if (m < L) {               // uniform across the wave (m is per-wave)
    int p = m + MM * ((L - 1 - m) / MM);   // last_pos; in [0, L-1]
    const float4* row = (const float4*)(enc + ((size_t)b * TT + p) * HH);
    const float4* qr = (const float4*)(qk + (size_t)b * HH);
    float4 a0 = row[lane], a1 = row[lane + 64];
    float4 b0 = qr[lane], b1 = qr[lane + 64];
    float acc = a0.x * b0.x + a0.y * b0.y + a0.z * b0.z + a0.w * b0.w +
                a1.x * b1.x + a1.y * b1.y + a1.z * b1.z + a1.w * b1.w;
#pragma unroll
    for (int off = 32; off; off >>= 1) acc += __shfl_down(acc, off);
    s = (acc + qbd) * INV_SQRT_H;
  } else {
    // invalid slot: memory row zeroed -> raw = q.k_b
    s = qbd * INV_SQRT_H;
  }
  if (lane == 0) scores[b * MM + m] = s;
}

// ---------------------------------------------------------------------------
// Per batch: top-8 (lowest-index tie-break, matching lax.top_k) done
// sync-free by wave 0 with all 2048 scores in registers; then softmax,
// retrieved + query, @ out_w + out_b with all 256 threads.
__global__ __launch_bounds__(256) void finalize_kernel(
    const float* __restrict__ enc, const float* __restrict__ scores,
    const float* __restrict__ query, const float* __restrict__ out_w,
    const float* __restrict__ out_b, const int* __restrict__ num_pairs,
    float* __restrict__ out) {
  int b = blockIdx.x, tid = threadIdx.x;
  int lane = tid & 63, wave = tid >> 6;
  __shared__ float pk[KK];   // normalized softmax probs
  __shared__ int pos[KK];    // gathered enc position, -1 if masked slot
  __shared__ __align__(16) float rq[HH];

  int L = min(2 * num_pairs[0], TT - 3);

  if (wave == 0) {
    // 32 scores per lane, m = lane + 64*i (ascending in i per lane)
    const float* srow = scores + (size_t)b * MM;
    float v[32];
#pragma unroll
    for (int i = 0; i < 32; ++i) v[i] = srow[lane + 64 * i];

    float topv[KK];
    int topi[KK];
#pragma unroll
    for (int k = 0; k < KK; ++k) {
      float best = -INFINITY;
      int bi = 0x7FFFFFFF;
#pragma unroll
      for (int i = 0; i < 32; ++i) {
        float x = v[i];
        if (x > best) { best = x; bi = lane + 64 * i; }  // strict > keeps lowest m
      }
#pragma unroll
      for (int off = 32; off; off >>= 1) {
        float ov = __shfl_down(best, off);
        int oi = __shfl_down(bi, off);
        if (ov > best || (ov == best && oi < bi)) { best = ov; bi = oi; }
      }
      best = __shfl(best, 0);
      bi = __shfl(bi, 0);
      topv[k] = best;
      topi[k] = bi;
      // clear chosen element in its owner lane (static reg indices only)
      int my = ((bi & 63) == lane) ? (bi >> 6) : -1;
#pragma unroll
      for (int i = 0; i < 32; ++i)
        if (i == my) v[i] = -INFINITY;
    }

    // softmax over the 8 kept values (all lanes have them; lane 0 writes)
    float mx = topv[0];
#pragma unroll
    for (int k = 1; k < KK; ++k) mx = fmaxf(mx, topv[k]);
    float p[KK];
    float se = 0.f;
#pragma unroll
    for (int k = 0; k < KK; ++k) { p[k] = expf(topv[k] - mx); se += p[k]; }
    float inv = 1.f / se;
    if (lane == 0) {
#pragma unroll
      for (int k = 0; k < KK; ++k) {
        pk[k] = p[k] * inv;
        int m = topi[k];
        pos[k] = (m < L) ? (m + MM * ((L - 1 - m) / MM)) : -1;
      }
    }
  }
  __syncthreads();

  // retrieved + query_hidden into LDS
  for (int h = tid; h < HH; h += 256) {
    float acc = query[b * HH + h];
#pragma unroll
    for (int k = 0; k < KK; ++k) {
      int pp = pos[k];
      if (pp >= 0)
        acc = fmaf(pk[k], enc[((size_t)b * TT + pp) * HH + h], acc);
    }
    rq[h] = acc;
  }
  __syncthreads();

  // logits = rq @ out_w + out_b   (coalesced over v)
  if (tid < VV) {
    float acc = out_b[tid];
#pragma unroll 8
    for (int h = 0; h < HH; ++h) acc = fmaf(rq[h], out_w[h * VV + tid], acc);
    out[b * VV + tid] = acc;
  }
}

// ---------------------------------------------------------------------------
extern "C" void kernel_launch(void* const* d_in, const int* in_sizes, int n_in,
                              void* d_out, int out_size, void* d_ws,
                              size_t ws_size, hipStream_t stream) {
  const float* enc = (const float*)d_in[0];
  const float* query = (const float*)d_in[1];
  const int* num_pairs = (const int*)d_in[2];
  const float* q_w = (const float*)d_in[3];
  const float* q_b = (const float*)d_in[4];
  const float* k_w = (const float*)d_in[5];
  const float* k_b = (const float*)d_in[6];
  const float* out_w = (const float*)d_in[7];
  const float* out_b = (const float*)d_in[8];
  float* out = (float*)d_out;

  char* ws = (char*)d_ws;
  float* qk = (float*)(ws);                // 32*512*4   = 64 KB
  float* qbd = (float*)(ws + 65536);       // 32*4       (padded to 1 KB)
  float* scores = (float*)(ws + 66560);    // 32*2048*4  = 256 KB

  hipLaunchKernelGGL(qk_kernel, dim3(BB), dim3(HH), 0, stream,
                     query, q_w, q_b, k_w, k_b, qk, qbd);
  hipLaunchKernelGGL(score_kernel, dim3(BB * MM / 4), dim3(256), 0, stream,
                     enc, qk, qbd, num_pairs, scores);
  hipLaunchKernelGGL(finalize_kernel, dim3(BB), dim3(256), 0, stream,
                     enc, scores, query, out_w, out_b, num_pairs, out);
}